// Round 6
// baseline (28.384 us; speedup 1.0000x reference)
//
#include <hip/hip_runtime.h>

// ---------------------------------------------------------------------------
// out = w .* mc + d * e0,   d = 0.5*ln(S1/S2) = 0.5*ln2*(log2 S1 - log2 S2)
// Swapped MFMA (16x16x32 f16):  D = Bmat^T * mc^T, so each lane's C/D regs
// hold 4 spectral cols of ONE mc-row -> column reduce is in-lane + 2 shfls.
//   A-op[i=col][k] = Bmat[k][col] ;  B-op[k][j=row] = mc[row][k]
//   Bmat[k<25][col<65]   = C[col][k]        (log2-domain freqt+cos)
//   Bmat[k<25][65<=c<130]= C[c-65][k]*w[k]  (w = 1,1,1.2,... ONSET=2)
//   Bmat[25][col]        = log2(bin wt): 0 bins 0,64; 1 else; -1e4 pads
// S1 = cols 0..64, S2 = cols 65..129, pads 130..143 -> exp2(-1e4)=0.
// (b2mc∘mc2b == I, so the 25x25 matmuls collapse; verified rounds 1-5.)
// No LDS staging: A-fragments load straight from global (contiguous 1600B
// per wave-instr = coalesced); LDS holds only the 256 d values.
// ---------------------------------------------------------------------------

namespace cg {

constexpr int L  = 128;
constexpr int M1 = 25;

struct CosTab { double v[L]; };
constexpr CosTab make_costab() {
    CosTab t{};
    const double PI = 3.14159265358979323846;
    for (int i = 0; i < L; ++i) {
        int j = (i <= 64) ? i : i - 128;
        double x = (2.0 * PI * (double)j) / 128.0;
        double x2 = x * x, term = 1.0, s = 1.0;
        for (int n = 1; n <= 16; ++n) {
            term *= -x2 / ((2.0 * n - 1.0) * (2.0 * n));
            s += term;
        }
        t.v[i] = s;
    }
    return t;
}
constexpr CosTab CT = make_costab();

struct AMat { double v[L][M1]; };
constexpr AMat make_aft() {
    AMat A{};
    const double al = -0.42;          // freqt called with -ALPHA
    double p = 1.0;
    for (int j = 0; j < M1; ++j) { A.v[0][j] = p; p *= al; }
    double q = 1.0;
    for (int j = 1; j < M1; ++j) { A.v[1][j] = q * (double)j * (1.0 - al * al); q *= al; }
    for (int i = 2; i < L; ++i)
        for (int j = 1; j < M1; ++j)
            A.v[i][j] = A.v[i - 1][j - 1] + al * (A.v[i][j - 1] - A.v[i - 1][j]);
    return A;
}
constexpr AMat AFT = make_aft();

struct Chunk { double v[8][M1]; };
template <int K0>
constexpr Chunk make_chunk() {
    Chunk c{};
    for (int kk = 0; kk < 8; ++kk) {
        int k = K0 + kk;
        for (int m = 0; m < M1; ++m) {
            double s = 0.0;
            for (int l = 0; l < L; ++l)
                s += AFT.v[l][m] * CT.v[(k * l) & 127];
            c.v[kk][m] = s;
        }
    }
    return c;
}
constexpr Chunk CH0 = make_chunk<0>();
constexpr Chunk CH1 = make_chunk<8>();
constexpr Chunk CH2 = make_chunk<16>();
constexpr Chunk CH3 = make_chunk<24>();
constexpr Chunk CH4 = make_chunk<32>();
constexpr Chunk CH5 = make_chunk<40>();
constexpr Chunk CH6 = make_chunk<48>();
constexpr Chunk CH7 = make_chunk<56>();
constexpr Chunk CH8 = make_chunk<64>();

constexpr double chunkval(int bin, int m) {
    const Chunk* chs[9] = { &CH0, &CH1, &CH2, &CH3, &CH4, &CH5, &CH6, &CH7, &CH8 };
    return chs[bin >> 3]->v[bin & 7][m];
}

constexpr double blogical(int k, int col) {
    const double LOG2E = 1.44269504088896340736;
    if (col >= 130) return (k == 25) ? -1.0e4 : 0.0;     // pad cols: exp2 -> 0
    int bin = (col < 65) ? col : (col - 65);
    if (k == 25) return (bin == 0 || bin == 64) ? 0.0 : 1.0;  // log2(bin wt)
    if (k > 25) return 0.0;
    double c = LOG2E * 2.0 * chunkval(bin, k);
    if (col >= 65 && k >= 2) c *= 1.2;                   // cepstral weight
    return c;
}

// constexpr float->half (RN-ish; accuracy far beyond what we need)
constexpr unsigned short f2h(double v) {
    if (v == 0.0) return 0;
    unsigned short s = 0;
    if (v < 0) { s = 0x8000; v = -v; }
    int e = 0;
    while (v >= 2.0) { v *= 0.5; ++e; }
    while (v < 1.0)  { v *= 2.0; --e; }
    if (e > 15) return (unsigned short)(s | 0x7c00);
    if (e < -14) return s;                               // flush tiny to 0
    int mant = (int)((v - 1.0) * 1024.0 + 0.5);
    if (mant == 1024) { mant = 0; ++e; if (e > 15) return (unsigned short)(s | 0x7c00); }
    return (unsigned short)(s | ((e + 15) << 10) | mant);
}

// A-operand fragment per tile: lane l, reg j holds A[i=l&15][k=(l>>4)*8+j]
//   = Bmat[(l>>4)*8+j][N*16 + (l&15)]
struct Tile { unsigned short v[64][8]; };
template <int N>
constexpr Tile make_tile() {
    Tile t{};
    for (int l = 0; l < 64; ++l)
        for (int j = 0; j < 8; ++j)
            t.v[l][j] = f2h(blogical((l >> 4) * 8 + j, N * 16 + (l & 15)));
    return t;
}
constexpr Tile T0 = make_tile<0>();
constexpr Tile T1 = make_tile<1>();
constexpr Tile T2 = make_tile<2>();
constexpr Tile T3 = make_tile<3>();
constexpr Tile T4 = make_tile<4>();
constexpr Tile T5 = make_tile<5>();
constexpr Tile T6 = make_tile<6>();
constexpr Tile T7 = make_tile<7>();
constexpr Tile T8 = make_tile<8>();

struct BH { alignas(16) unsigned short v[9][64][8]; };
constexpr BH make_bh() {
    BH b{};
    const Tile* ts[9] = { &T0, &T1, &T2, &T3, &T4, &T5, &T6, &T7, &T8 };
    for (int n = 0; n < 9; ++n)
        for (int l = 0; l < 64; ++l)
            for (int j = 0; j < 8; ++j)
                b.v[n][l][j] = ts[n]->v[l][j];
    return b;
}

} // namespace cg

__device__ const cg::BH g_Bh = cg::make_bh();

typedef _Float16 f16x8 __attribute__((ext_vector_type(8)));
typedef float    f32x4 __attribute__((ext_vector_type(4)));
typedef float    f32x4u __attribute__((ext_vector_type(4), aligned(4)));  // 4B-ok

// ---------------------------------------------------------------------------
// 256 threads = 4 waves; block = 256 rows. Wave wv: rows [wv*64, wv*64+64)
// as 4 groups of 16 rows.
// ---------------------------------------------------------------------------
__global__ __launch_bounds__(256, 8)
void mcpf_kernel(const float* __restrict__ mc, float* __restrict__ out) {
    __shared__ float d_lds[272];                   // only cross-thread data
    const int tid = threadIdx.x;
    const long long base = (long long)blockIdx.x * (256LL * 25);

    const int lane = tid & 63;
    const int wv   = tid >> 6;
    const int r0   = lane & 15;     // mc-row within 16-group
    const int kg   = lane >> 4;     // K group 0..3 (also col subgroup in D)

    // B-matrix fragments, pre-swizzled + pre-converted: 9x 16B loads
    f16x8 bfrag[9];
#pragma unroll
    for (int n = 0; n < 9; ++n)
        bfrag[n] = *reinterpret_cast<const f16x8*>(&g_Bh.v[n][lane][0]);

#pragma unroll
    for (int g = 0; g < 4; ++g) {
        const int rowbase = wv * 64 + g * 16;
        const float* __restrict__ arow = mc + base + (rowbase + r0) * 25;

        // data fragment (B-operand) straight from global:
        // lane holds row r0, k = kg*8 + j
        f16x8 af;
        if (kg < 3) {
            f32x4u f0 = *reinterpret_cast<const f32x4u*>(arow + kg * 8);
            f32x4u f1 = *reinterpret_cast<const f32x4u*>(arow + kg * 8 + 4);
            af[0] = (_Float16)f0.x; af[1] = (_Float16)f0.y;
            af[2] = (_Float16)f0.z; af[3] = (_Float16)f0.w;
            af[4] = (_Float16)f1.x; af[5] = (_Float16)f1.y;
            af[6] = (_Float16)f1.z; af[7] = (_Float16)f1.w;
        } else {
            af[0] = (_Float16)arow[24];      // k=24
            af[1] = (_Float16)1.0f;          // k=25: constant column for lw
#pragma unroll
            for (int j = 2; j < 8; ++j) af[j] = (_Float16)0.0f;
        }

        // D[col][row]: this lane gets row r0, cols n*16 + kg*4 + r
        float s1 = 0.0f, s2 = 0.0f;
#pragma unroll
        for (int n = 0; n < 9; ++n) {
            f32x4 acc = {0.f, 0.f, 0.f, 0.f};
            acc = __builtin_amdgcn_mfma_f32_16x16x32_f16(bfrag[n], af, acc, 0, 0, 0);
#pragma unroll
            for (int r = 0; r < 4; ++r) {
                float e = __builtin_amdgcn_exp2f(acc[r]);
                if (n < 4) {
                    s1 += e;                           // cols 0..63
                } else if (n == 4 && r == 0) {
                    bool c = (kg == 0);                // col 64 -> S1
                    s1 += c ? e : 0.0f;
                    s2 += c ? 0.0f : e;
                } else {
                    s2 += e;                           // cols 65..143 (pads->0)
                }
            }
        }

        // cross-kg reduce: butterfly over lane bits 4,5
        s1 += __shfl_xor(s1, 16);
        s1 += __shfl_xor(s1, 32);
        s2 += __shfl_xor(s2, 16);
        s2 += __shfl_xor(s2, 32);

        if (kg == 0) {
            float d = 0.34657359027997264f *
                      (__builtin_amdgcn_logf(s1) - __builtin_amdgcn_logf(s2));
            d_lds[rowbase + r0] = d;
        }
    }

    __syncthreads();

    // fused store-out: out = w .* mc + d on element 0 of each row.
    // mc re-read as aligned float4 (L2-resident from phase 1).
    const float4* __restrict__ src4 = reinterpret_cast<const float4*>(mc + base);
    float4* __restrict__ dst4 = reinterpret_cast<float4*>(out + base);
#pragma unroll
    for (int i = 0; i < 7; ++i) {
        int idx = tid + i * 256;
        if (idx < 1600) {
            float4 v = src4[idx];
            int f = idx * 4;
            int q = f / 25;
            int r = f - 25 * q;
            float dv0 = d_lds[q];
            float dv1 = d_lds[q + 1];              // in-bounds (<=256, padded)
            // w per component: 1 for cepstral index 0,1 else 1.2
            v.x *= (r     < 2)              ? 1.0f : 1.2f;
            v.y *= (r + 1 < 2 || r + 1 == 25) ? 1.0f : 1.2f;
            v.z *= (r + 2 == 25 || r + 2 == 26) ? 1.0f : 1.2f;
            v.w *= (r + 3 == 25 || r + 3 == 26) ? 1.0f : 1.2f;
            // +d on cepstral index 0 (w=1 there)
            if (r == 0)  v.x += dv0;
            if (r == 22) v.w += dv1;
            if (r == 23) v.z += dv1;
            if (r == 24) v.y += dv1;
            dst4[idx] = v;
        }
    }
}

extern "C" void kernel_launch(void* const* d_in, const int* in_sizes, int n_in,
                              void* d_out, int out_size, void* d_ws, size_t ws_size,
                              hipStream_t stream) {
    const float* mc = (const float*)d_in[0];
    float* out = (float*)d_out;
    const int rows = in_sizes[0] / 25;             // 524288
    const int blocks = rows / 256;                 // 2048
    mcpf_kernel<<<dim3(blocks), dim3(256), 0, stream>>>(mc, out);
}

// Round 7
// 26.171 us; speedup vs baseline: 1.0845x; 1.0845x over previous
//
#include <hip/hip_runtime.h>

// ---------------------------------------------------------------------------
// out = w .* mc + d * e0,   d = 0.5*ln(S1/S2) = 0.5*ln2*(log2 S1 - log2 S2)
// Swapped MFMA (16x16x32 f16):  D = Bmat^T * mc^T, so each lane's C/D regs
// hold 4 spectral cols of ONE mc-row -> column reduce is in-lane + 2 shfls.
//   A-op[i=col][k] = Bmat[k][col] ;  B-op[k][j=row] = mc[row][k]
//   Bmat[k<25][col<65]   = C[col][k]        (log2-domain freqt+cos)
//   Bmat[k<25][65<=c<130]= C[c-65][k]*w[k]  (w = 1,1,1.2,... ONSET=2)
//   Bmat[25][col]        = log2(bin wt): 0 bins 0,64; 1 else; -1e4 pads
// S1 = cols 0..64, S2 = cols 65..129, pads 130..143 -> exp2(-1e4)=0.
// (b2mc∘mc2b == I, so the 25x25 matmuls collapse; verified rounds 1-6.)
// Single global read: stage-in keeps float4s in registers for the epilogue;
// LDS used once for the row-major -> fragment exchange + the 256 d values.
// ---------------------------------------------------------------------------

namespace cg {

constexpr int L  = 128;
constexpr int M1 = 25;

struct CosTab { double v[L]; };
constexpr CosTab make_costab() {
    CosTab t{};
    const double PI = 3.14159265358979323846;
    for (int i = 0; i < L; ++i) {
        int j = (i <= 64) ? i : i - 128;
        double x = (2.0 * PI * (double)j) / 128.0;
        double x2 = x * x, term = 1.0, s = 1.0;
        for (int n = 1; n <= 16; ++n) {
            term *= -x2 / ((2.0 * n - 1.0) * (2.0 * n));
            s += term;
        }
        t.v[i] = s;
    }
    return t;
}
constexpr CosTab CT = make_costab();

struct AMat { double v[L][M1]; };
constexpr AMat make_aft() {
    AMat A{};
    const double al = -0.42;          // freqt called with -ALPHA
    double p = 1.0;
    for (int j = 0; j < M1; ++j) { A.v[0][j] = p; p *= al; }
    double q = 1.0;
    for (int j = 1; j < M1; ++j) { A.v[1][j] = q * (double)j * (1.0 - al * al); q *= al; }
    for (int i = 2; i < L; ++i)
        for (int j = 1; j < M1; ++j)
            A.v[i][j] = A.v[i - 1][j - 1] + al * (A.v[i][j - 1] - A.v[i - 1][j]);
    return A;
}
constexpr AMat AFT = make_aft();

struct Chunk { double v[8][M1]; };
template <int K0>
constexpr Chunk make_chunk() {
    Chunk c{};
    for (int kk = 0; kk < 8; ++kk) {
        int k = K0 + kk;
        for (int m = 0; m < M1; ++m) {
            double s = 0.0;
            for (int l = 0; l < L; ++l)
                s += AFT.v[l][m] * CT.v[(k * l) & 127];
            c.v[kk][m] = s;
        }
    }
    return c;
}
constexpr Chunk CH0 = make_chunk<0>();
constexpr Chunk CH1 = make_chunk<8>();
constexpr Chunk CH2 = make_chunk<16>();
constexpr Chunk CH3 = make_chunk<24>();
constexpr Chunk CH4 = make_chunk<32>();
constexpr Chunk CH5 = make_chunk<40>();
constexpr Chunk CH6 = make_chunk<48>();
constexpr Chunk CH7 = make_chunk<56>();
constexpr Chunk CH8 = make_chunk<64>();

constexpr double chunkval(int bin, int m) {
    const Chunk* chs[9] = { &CH0, &CH1, &CH2, &CH3, &CH4, &CH5, &CH6, &CH7, &CH8 };
    return chs[bin >> 3]->v[bin & 7][m];
}

constexpr double blogical(int k, int col) {
    const double LOG2E = 1.44269504088896340736;
    if (col >= 130) return (k == 25) ? -1.0e4 : 0.0;     // pad cols: exp2 -> 0
    int bin = (col < 65) ? col : (col - 65);
    if (k == 25) return (bin == 0 || bin == 64) ? 0.0 : 1.0;  // log2(bin wt)
    if (k > 25) return 0.0;
    double c = LOG2E * 2.0 * chunkval(bin, k);
    if (col >= 65 && k >= 2) c *= 1.2;                   // cepstral weight
    return c;
}

// constexpr float->half (RN-ish; accuracy far beyond what we need)
constexpr unsigned short f2h(double v) {
    if (v == 0.0) return 0;
    unsigned short s = 0;
    if (v < 0) { s = 0x8000; v = -v; }
    int e = 0;
    while (v >= 2.0) { v *= 0.5; ++e; }
    while (v < 1.0)  { v *= 2.0; --e; }
    if (e > 15) return (unsigned short)(s | 0x7c00);
    if (e < -14) return s;                               // flush tiny to 0
    int mant = (int)((v - 1.0) * 1024.0 + 0.5);
    if (mant == 1024) { mant = 0; ++e; if (e > 15) return (unsigned short)(s | 0x7c00); }
    return (unsigned short)(s | ((e + 15) << 10) | mant);
}

// A-operand fragment per tile: lane l, reg j holds A[i=l&15][k=(l>>4)*8+j]
//   = Bmat[(l>>4)*8+j][N*16 + (l&15)]
struct Tile { unsigned short v[64][8]; };
template <int N>
constexpr Tile make_tile() {
    Tile t{};
    for (int l = 0; l < 64; ++l)
        for (int j = 0; j < 8; ++j)
            t.v[l][j] = f2h(blogical((l >> 4) * 8 + j, N * 16 + (l & 15)));
    return t;
}
constexpr Tile T0 = make_tile<0>();
constexpr Tile T1 = make_tile<1>();
constexpr Tile T2 = make_tile<2>();
constexpr Tile T3 = make_tile<3>();
constexpr Tile T4 = make_tile<4>();
constexpr Tile T5 = make_tile<5>();
constexpr Tile T6 = make_tile<6>();
constexpr Tile T7 = make_tile<7>();
constexpr Tile T8 = make_tile<8>();

struct BH { alignas(16) unsigned short v[9][64][8]; };
constexpr BH make_bh() {
    BH b{};
    const Tile* ts[9] = { &T0, &T1, &T2, &T3, &T4, &T5, &T6, &T7, &T8 };
    for (int n = 0; n < 9; ++n)
        for (int l = 0; l < 64; ++l)
            for (int j = 0; j < 8; ++j)
                b.v[n][l][j] = ts[n]->v[l][j];
    return b;
}

} // namespace cg

__device__ const cg::BH g_Bh = cg::make_bh();

typedef _Float16 f16x8 __attribute__((ext_vector_type(8)));
typedef float    f32x4 __attribute__((ext_vector_type(4)));

// ---------------------------------------------------------------------------
// 256 threads = 4 waves; block = 256 rows. Wave wv: rows [wv*64, wv*64+64)
// as 4 groups of 16 rows.
// ---------------------------------------------------------------------------
__global__ __launch_bounds__(256, 5)
void mcpf_kernel(const float* __restrict__ mc, float* __restrict__ out) {
    __shared__ __align__(16) float sbuf[256 * 25 + 8];   // 25.6 KB (+pad)
    __shared__ float d_lds[272];
    const int tid = threadIdx.x;
    const long long base = (long long)blockIdx.x * (256LL * 25);

    const int lane = tid & 63;
    const int wv   = tid >> 6;
    const int r0   = lane & 15;     // mc-row within 16-group
    const int kg   = lane >> 4;     // K group 0..3 (also col subgroup in D)

    // B-matrix fragments (rodata, L2-resident): 9x 16B loads
    f16x8 bfrag[9];
#pragma unroll
    for (int n = 0; n < 9; ++n)
        bfrag[n] = *reinterpret_cast<const f16x8*>(&g_Bh.v[n][lane][0]);

    // single coalesced global read; KEEP in registers for the epilogue
    const float4* __restrict__ src4 = reinterpret_cast<const float4*>(mc + base);
    float4* sb4 = reinterpret_cast<float4*>(sbuf);
    float4 rowreg[7];
#pragma unroll
    for (int i = 0; i < 7; ++i) {
        int idx = tid + i * 256;
        if (idx < 1600) {
            rowreg[i] = src4[idx];
            sb4[idx]  = rowreg[i];
        }
    }
    __syncthreads();

#pragma unroll
    for (int g = 0; g < 4; ++g) {
        const int rowbase = wv * 64 + g * 16;
        const float* __restrict__ arow = &sbuf[(rowbase + r0) * 25 + kg * 8];

        // data fragment (B-operand): lane holds row r0, k = kg*8 + j.
        // All lanes read 8 dwords (kg==3 overreads into next row / pad, then
        // fixed up branchlessly). Stride-25 dwords -> <=2-way bank alias.
        float tmp[8];
#pragma unroll
        for (int j = 0; j < 8; ++j) tmp[j] = arow[j];
        f16x8 af;
        af[0] = (_Float16)tmp[0];
        af[1] = (kg == 3) ? (_Float16)1.0f : (_Float16)tmp[1];
#pragma unroll
        for (int j = 2; j < 8; ++j)
            af[j] = (kg == 3) ? (_Float16)0.0f : (_Float16)tmp[j];

        // D[col][row]: this lane gets row r0, cols n*16 + kg*4 + r
        float s1 = 0.0f, s2 = 0.0f;
#pragma unroll
        for (int n = 0; n < 9; ++n) {
            f32x4 acc = {0.f, 0.f, 0.f, 0.f};
            acc = __builtin_amdgcn_mfma_f32_16x16x32_f16(bfrag[n], af, acc, 0, 0, 0);
            float e0 = __builtin_amdgcn_exp2f(acc[0]);
            float e1 = __builtin_amdgcn_exp2f(acc[1]);
            float e2 = __builtin_amdgcn_exp2f(acc[2]);
            float e3 = __builtin_amdgcn_exp2f(acc[3]);
            if (n < 4) {
                s1 += (e0 + e1) + (e2 + e3);           // cols 0..63
            } else if (n == 4) {                       // col 64 (kg0,r0) -> S1
                float h = (e0 + e1) + (e2 + e3);
                bool c = (kg == 0);
                s1 += c ? e0 : 0.0f;
                s2 += c ? (h - e0) : h;
            } else {
                s2 += (e0 + e1) + (e2 + e3);           // cols 80..143 (pads->0)
            }
        }

        // cross-kg reduce: butterfly over lane bits 4,5
        s1 += __shfl_xor(s1, 16);
        s1 += __shfl_xor(s1, 32);
        s2 += __shfl_xor(s2, 16);
        s2 += __shfl_xor(s2, 32);

        if (kg == 0) {
            float d = 0.34657359027997264f *
                      (__builtin_amdgcn_logf(s1) - __builtin_amdgcn_logf(s2));
            d_lds[rowbase + r0] = d;
        }
    }

    __syncthreads();

    // fused store-out from the registers staged in phase A:
    // out = w .* mc, +d on cepstral element 0 of each row.
    float4* __restrict__ dst4 = reinterpret_cast<float4*>(out + base);
#pragma unroll
    for (int i = 0; i < 7; ++i) {
        int idx = tid + i * 256;
        if (idx < 1600) {
            float4 v = rowreg[i];
            int f = idx * 4;
            int q = f / 25;
            int r = f - 25 * q;
            float dv0 = d_lds[q];
            float dv1 = d_lds[q + 1];              // in-bounds (<=256, padded)
            // w per component: 1 for cepstral index 0,1 else 1.2
            v.x *= (r     < 2)                  ? 1.0f : 1.2f;
            v.y *= (r + 1 < 2 || r + 1 == 25)   ? 1.0f : 1.2f;
            v.z *= (r + 2 == 25 || r + 2 == 26) ? 1.0f : 1.2f;
            v.w *= (r + 3 == 25 || r + 3 == 26) ? 1.0f : 1.2f;
            // +d on cepstral index 0 (w=1 there)
            if (r == 0)  v.x += dv0;
            if (r == 22) v.w += dv1;
            if (r == 23) v.z += dv1;
            if (r == 24) v.y += dv1;
            dst4[idx] = v;
        }
    }
}

extern "C" void kernel_launch(void* const* d_in, const int* in_sizes, int n_in,
                              void* d_out, int out_size, void* d_ws, size_t ws_size,
                              hipStream_t stream) {
    const float* mc = (const float*)d_in[0];
    float* out = (float*)d_out;
    const int rows = in_sizes[0] / 25;             // 524288
    const int blocks = rows / 256;                 // 2048
    mcpf_kernel<<<dim3(blocks), dim3(256), 0, stream>>>(mc, out);
}

// Round 8
// 24.539 us; speedup vs baseline: 1.1567x; 1.0665x over previous
//
#include <hip/hip_runtime.h>

// ---------------------------------------------------------------------------
// out = w .* mc + d * e0,   d = 0.5*ln(S1/S2) = 0.5*ln2*(log2 S1 - log2 S2)
// Swapped MFMA (16x16x32 f16):  D = Bmat^T * mc^T, so each lane's C/D regs
// hold 4 spectral cols of ONE mc-row -> column reduce is in-lane + 2 shfls.
//   A-op[i=col][k] = Bmat[k][col] ;  B-op[k][j=row] = mc[row][k]
//   Bmat[k<25][col<65]   = C[col][k]        (log2-domain freqt+cos)
//   Bmat[k<25][65<=c<130]= C[c-65][k]*w[k]  (w = 1,1,1.2,... ONSET=2)
//   Bmat[25][col]        = log2(bin wt): 0 bins 0,64; 1 else; -1e4 pads
// S1 = cols 0..64, S2 = cols 65..129, pads 130..143 -> exp2(-1e4)=0.
// (b2mc∘mc2b == I, so the 25x25 matmuls collapse; verified rounds 1-7.)
// WAVE-INDEPENDENT: each wave stages its own 64 rows in its own LDS chunk,
// computes, and stores them. No __syncthreads anywhere -- intra-wave LDS
// RAW ordering via s_waitcnt lgkmcnt(0). Waves desync -> loads/stores spread
// across the kernel instead of bunching at barrier edges.
// ---------------------------------------------------------------------------

namespace cg {

constexpr int L  = 128;
constexpr int M1 = 25;

struct CosTab { double v[L]; };
constexpr CosTab make_costab() {
    CosTab t{};
    const double PI = 3.14159265358979323846;
    for (int i = 0; i < L; ++i) {
        int j = (i <= 64) ? i : i - 128;
        double x = (2.0 * PI * (double)j) / 128.0;
        double x2 = x * x, term = 1.0, s = 1.0;
        for (int n = 1; n <= 16; ++n) {
            term *= -x2 / ((2.0 * n - 1.0) * (2.0 * n));
            s += term;
        }
        t.v[i] = s;
    }
    return t;
}
constexpr CosTab CT = make_costab();

struct AMat { double v[L][M1]; };
constexpr AMat make_aft() {
    AMat A{};
    const double al = -0.42;          // freqt called with -ALPHA
    double p = 1.0;
    for (int j = 0; j < M1; ++j) { A.v[0][j] = p; p *= al; }
    double q = 1.0;
    for (int j = 1; j < M1; ++j) { A.v[1][j] = q * (double)j * (1.0 - al * al); q *= al; }
    for (int i = 2; i < L; ++i)
        for (int j = 1; j < M1; ++j)
            A.v[i][j] = A.v[i - 1][j - 1] + al * (A.v[i][j - 1] - A.v[i - 1][j]);
    return A;
}
constexpr AMat AFT = make_aft();

struct Chunk { double v[8][M1]; };
template <int K0>
constexpr Chunk make_chunk() {
    Chunk c{};
    for (int kk = 0; kk < 8; ++kk) {
        int k = K0 + kk;
        for (int m = 0; m < M1; ++m) {
            double s = 0.0;
            for (int l = 0; l < L; ++l)
                s += AFT.v[l][m] * CT.v[(k * l) & 127];
            c.v[kk][m] = s;
        }
    }
    return c;
}
constexpr Chunk CH0 = make_chunk<0>();
constexpr Chunk CH1 = make_chunk<8>();
constexpr Chunk CH2 = make_chunk<16>();
constexpr Chunk CH3 = make_chunk<24>();
constexpr Chunk CH4 = make_chunk<32>();
constexpr Chunk CH5 = make_chunk<40>();
constexpr Chunk CH6 = make_chunk<48>();
constexpr Chunk CH7 = make_chunk<56>();
constexpr Chunk CH8 = make_chunk<64>();

constexpr double chunkval(int bin, int m) {
    const Chunk* chs[9] = { &CH0, &CH1, &CH2, &CH3, &CH4, &CH5, &CH6, &CH7, &CH8 };
    return chs[bin >> 3]->v[bin & 7][m];
}

constexpr double blogical(int k, int col) {
    const double LOG2E = 1.44269504088896340736;
    if (col >= 130) return (k == 25) ? -1.0e4 : 0.0;     // pad cols: exp2 -> 0
    int bin = (col < 65) ? col : (col - 65);
    if (k == 25) return (bin == 0 || bin == 64) ? 0.0 : 1.0;  // log2(bin wt)
    if (k > 25) return 0.0;
    double c = LOG2E * 2.0 * chunkval(bin, k);
    if (col >= 65 && k >= 2) c *= 1.2;                   // cepstral weight
    return c;
}

// constexpr float->half (RN-ish; accuracy far beyond what we need)
constexpr unsigned short f2h(double v) {
    if (v == 0.0) return 0;
    unsigned short s = 0;
    if (v < 0) { s = 0x8000; v = -v; }
    int e = 0;
    while (v >= 2.0) { v *= 0.5; ++e; }
    while (v < 1.0)  { v *= 2.0; --e; }
    if (e > 15) return (unsigned short)(s | 0x7c00);
    if (e < -14) return s;                               // flush tiny to 0
    int mant = (int)((v - 1.0) * 1024.0 + 0.5);
    if (mant == 1024) { mant = 0; ++e; if (e > 15) return (unsigned short)(s | 0x7c00); }
    return (unsigned short)(s | ((e + 15) << 10) | mant);
}

// A-operand fragment per tile: lane l, reg j holds A[i=l&15][k=(l>>4)*8+j]
//   = Bmat[(l>>4)*8+j][N*16 + (l&15)]
struct Tile { unsigned short v[64][8]; };
template <int N>
constexpr Tile make_tile() {
    Tile t{};
    for (int l = 0; l < 64; ++l)
        for (int j = 0; j < 8; ++j)
            t.v[l][j] = f2h(blogical((l >> 4) * 8 + j, N * 16 + (l & 15)));
    return t;
}
constexpr Tile T0 = make_tile<0>();
constexpr Tile T1 = make_tile<1>();
constexpr Tile T2 = make_tile<2>();
constexpr Tile T3 = make_tile<3>();
constexpr Tile T4 = make_tile<4>();
constexpr Tile T5 = make_tile<5>();
constexpr Tile T6 = make_tile<6>();
constexpr Tile T7 = make_tile<7>();
constexpr Tile T8 = make_tile<8>();

struct BH { alignas(16) unsigned short v[9][64][8]; };
constexpr BH make_bh() {
    BH b{};
    const Tile* ts[9] = { &T0, &T1, &T2, &T3, &T4, &T5, &T6, &T7, &T8 };
    for (int n = 0; n < 9; ++n)
        for (int l = 0; l < 64; ++l)
            for (int j = 0; j < 8; ++j)
                b.v[n][l][j] = ts[n]->v[l][j];
    return b;
}

} // namespace cg

__device__ const cg::BH g_Bh = cg::make_bh();

typedef _Float16 f16x8 __attribute__((ext_vector_type(8)));
typedef float    f32x4 __attribute__((ext_vector_type(4)));

// per-wave LDS chunk: 64 rows x 25 floats, then 66 d-slots, pad to 1672
constexpr int WCHUNK = 1672;

// ---------------------------------------------------------------------------
// 256 threads = 4 independent waves; each wave owns 64 rows end-to-end.
// ---------------------------------------------------------------------------
__global__ __launch_bounds__(256, 6)
void mcpf_kernel(const float* __restrict__ mc, float* __restrict__ out) {
    __shared__ __align__(16) float sbuf[4 * WCHUNK];     // 26.8 KB
    const int tid  = threadIdx.x;
    const int lane = tid & 63;
    const int wv   = tid >> 6;
    const int r0   = lane & 15;     // mc-row within 16-group
    const int kg   = lane >> 4;     // K group 0..3 (also col subgroup in D)

    float* __restrict__ wbuf = &sbuf[wv * WCHUNK];       // this wave's chunk
    float* __restrict__ dreg = wbuf + 1600;              // 64(+2) d values

    // global float4 base for this wave's 64 rows (64*25 floats = 400 float4)
    const long long base4 = (long long)blockIdx.x * 1600 + wv * 400;

    // B-matrix fragments (rodata, L2-resident): 9x 16B loads
    f16x8 bfrag[9];
#pragma unroll
    for (int n = 0; n < 9; ++n)
        bfrag[n] = *reinterpret_cast<const f16x8*>(&g_Bh.v[n][lane][0]);

    // wave-local coalesced stage-in: 400 float4 = 6x64 + 16
    const float4* __restrict__ src4 =
        reinterpret_cast<const float4*>(mc) + base4;
    float4* wb4 = reinterpret_cast<float4*>(wbuf);
#pragma unroll
    for (int j = 0; j < 7; ++j) {
        int idx = lane + j * 64;
        if (idx < 400) wb4[idx] = src4[idx];
    }
    // intra-wave RAW: wait for own ds_writes to land (no block barrier)
    asm volatile("s_waitcnt lgkmcnt(0)" ::: "memory");

#pragma unroll
    for (int g = 0; g < 4; ++g) {
        const int rowbase = g * 16;
        const float* __restrict__ arow = &wbuf[(rowbase + r0) * 25 + kg * 8];

        // data fragment (B-operand): lane holds row r0, k = kg*8 + j.
        // kg==3 overreads into next row / d-region, fixed up branchlessly.
        float tmp[8];
#pragma unroll
        for (int j = 0; j < 8; ++j) tmp[j] = arow[j];
        f16x8 af;
        af[0] = (_Float16)tmp[0];
        af[1] = (kg == 3) ? (_Float16)1.0f : (_Float16)tmp[1];
#pragma unroll
        for (int j = 2; j < 8; ++j)
            af[j] = (kg == 3) ? (_Float16)0.0f : (_Float16)tmp[j];

        // D[col][row]: this lane gets row r0, cols n*16 + kg*4 + r
        float s1 = 0.0f, s2 = 0.0f;
#pragma unroll
        for (int n = 0; n < 9; ++n) {
            f32x4 acc = {0.f, 0.f, 0.f, 0.f};
            acc = __builtin_amdgcn_mfma_f32_16x16x32_f16(bfrag[n], af, acc, 0, 0, 0);
            float e0 = __builtin_amdgcn_exp2f(acc[0]);
            float e1 = __builtin_amdgcn_exp2f(acc[1]);
            float e2 = __builtin_amdgcn_exp2f(acc[2]);
            float e3 = __builtin_amdgcn_exp2f(acc[3]);
            if (n < 4) {
                s1 += (e0 + e1) + (e2 + e3);           // cols 0..63
            } else if (n == 4) {                       // col 64 (kg0,r0) -> S1
                float h = (e0 + e1) + (e2 + e3);
                bool c = (kg == 0);
                s1 += c ? e0 : 0.0f;
                s2 += c ? (h - e0) : h;
            } else {
                s2 += (e0 + e1) + (e2 + e3);           // cols 80..143 (pads->0)
            }
        }

        // cross-kg reduce: butterfly over lane bits 4,5
        s1 += __shfl_xor(s1, 16);
        s1 += __shfl_xor(s1, 32);
        s2 += __shfl_xor(s2, 16);
        s2 += __shfl_xor(s2, 32);

        if (kg == 0) {
            float d = 0.34657359027997264f *
                      (__builtin_amdgcn_logf(s1) - __builtin_amdgcn_logf(s2));
            dreg[rowbase + r0] = d;
        }
    }

    // intra-wave RAW on the d values
    asm volatile("s_waitcnt lgkmcnt(0)" ::: "memory");

    // fused store-out: re-read staged rows from own LDS chunk,
    // out = w .* mc, +d on cepstral element 0 of each row.
    float4* __restrict__ dst4 = reinterpret_cast<float4*>(out) + base4;
#pragma unroll
    for (int j = 0; j < 7; ++j) {
        int idx = lane + j * 64;
        if (idx < 400) {
            float4 v = wb4[idx];
            int f = idx * 4;                           // wave-local float idx
            int q = f / 25;                            // wave-local row
            int r = f - 25 * q;
            float dv0 = dreg[q];
            float dv1 = dreg[q + 1];                   // <=64: padded slot
            // w per component: 1 for cepstral index 0,1 else 1.2
            v.x *= (r     < 2)                  ? 1.0f : 1.2f;
            v.y *= (r + 1 < 2 || r + 1 == 25)   ? 1.0f : 1.2f;
            v.z *= (r + 2 == 25 || r + 2 == 26) ? 1.0f : 1.2f;
            v.w *= (r + 3 == 25 || r + 3 == 26) ? 1.0f : 1.2f;
            // +d on cepstral index 0 (w=1 there)
            if (r == 0)  v.x += dv0;
            if (r == 22) v.w += dv1;
            if (r == 23) v.z += dv1;
            if (r == 24) v.y += dv1;
            dst4[idx] = v;
        }
    }
}

extern "C" void kernel_launch(void* const* d_in, const int* in_sizes, int n_in,
                              void* d_out, int out_size, void* d_ws, size_t ws_size,
                              hipStream_t stream) {
    const float* mc = (const float*)d_in[0];
    float* out = (float*)d_out;
    const int rows = in_sizes[0] / 25;             // 524288
    const int blocks = rows / 256;                 // 2048
    mcpf_kernel<<<dim3(blocks), dim3(256), 0, stream>>>(mc, out);
}